// Round 1
// baseline (252.693 us; speedup 1.0000x reference)
//
#include <hip/hip_runtime.h>
#include <hip/hip_bf16.h>

// Problem constants: B=32, T=256, N=1024 -> R = 8192 rows, K = N-1 = 1023 (padded to 1024)
// alpha = 0.5, b[m] = sqrt(m+1)-sqrt(m), coef = sqrt(1023)/Gamma(1.5)
#define COEF 36.090511f
#define INV_COUNT (1.0f / 8388608.0f)   // 1 / (32*256*1024)

typedef __attribute__((ext_vector_type(4))) float f32x4;
typedef __attribute__((ext_vector_type(8))) __bf16 bf16x8;

typedef const __attribute__((address_space(1))) unsigned int* gas_ptr;
typedef __attribute__((address_space(3))) unsigned int* las_ptr;

__device__ __forceinline__ void load_lds16(const void* g, void* l) {
  // 16B direct global->LDS (dest is wave-uniform base + lane*16; our lds ptr = base + lane*16 so lane0 == base)
  __builtin_amdgcn_global_load_lds((gas_ptr)g, (las_ptr)l, 16, 0, 0);
}

__global__ void zero_accums(float* a) {
  if (threadIdx.x < 2) a[threadIdx.x] = 0.f;
}

// Mt[i][j] = b[i-j] for j <= i, else 0.  (transposed Toeplitz so B-tiles are [col][k] row-major)
__global__ void build_mt(__hip_bfloat16* __restrict__ Mt) {
  int idx = blockIdx.x * 256 + threadIdx.x;   // 1024*1024 elements
  int i = idx >> 10;
  int j = idx & 1023;
  int m = i - j;
  float v = (m >= 0) ? (sqrtf((float)(m + 1)) - sqrtf((float)m)) : 0.f;
  Mt[idx] = __float2bfloat16(v);
}

// du (bf16, padded col 1023 = 0), data-loss partial sums, and the n=0 physics term (u_t[r,0]^2 = du[r,0]^2).
__global__ void prep(const float* __restrict__ up, const float* __restrict__ utr,
                     __hip_bfloat16* __restrict__ du, float* __restrict__ accums) {
  const int r = blockIdx.x;       // 8192 rows
  const int t = threadIdx.x;      // 256 threads
  const int j0 = t * 4;
  const float* rowp = up + (size_t)r * 1024;

  f32x4 a = *(const f32x4*)(rowp + j0);
  float a4 = (t < 255) ? rowp[j0 + 4] : 0.f;
  f32x4 b = *(const f32x4*)(utr + (size_t)r * 1024 + j0);

  float d0 = a[1] - a[0];
  float d1 = a[2] - a[1];
  float d2 = a[3] - a[2];
  float d3 = (t < 255) ? (a4 - a[3]) : 0.f;   // du[1023] = 0 pad

  union { ushort4 u4; __hip_bfloat16 h[4]; } pk;
  pk.h[0] = __float2bfloat16(d0);
  pk.h[1] = __float2bfloat16(d1);
  pk.h[2] = __float2bfloat16(d2);
  pk.h[3] = __float2bfloat16(d3);
  *(ushort4*)(du + (size_t)r * 1024 + j0) = pk.u4;

  float e0 = a[0] - b[0], e1 = a[1] - b[1], e2 = a[2] - b[2], e3 = a[3] - b[3];
  float dsum = e0 * e0 + e1 * e1 + e2 * e2 + e3 * e3;

#pragma unroll
  for (int off = 32; off > 0; off >>= 1) dsum += __shfl_down(dsum, off, 64);
  __shared__ float ws4[4];
  const int lane = t & 63, w = t >> 6;
  if (lane == 0) ws4[w] = dsum;
  __syncthreads();
  if (t == 0) {
    atomicAdd(&accums[0], ws4[0] + ws4[1] + ws4[2] + ws4[3]);
    atomicAdd(&accums[1], d0 * d0);   // physics residual at n=0 is u_t = du[r,0] (frac_lap[0] = 0)
  }
}

// Y[r,i] = sum_j du[r,j] * b[i-j]; fused epilogue: resid = u_t - COEF*Y, accumulate resid^2.
// 128x128 tile, BK=32, 4 waves (2x2 of 64x64), double-buffered LDS, triangular K-skip.
__launch_bounds__(256, 2)
__global__ void gemm(const __hip_bfloat16* __restrict__ du,
                     const __hip_bfloat16* __restrict__ Mt,
                     float* __restrict__ accums) {
  __shared__ __hip_bfloat16 sA[2][4096];   // [128 rows][32 k]
  __shared__ __hip_bfloat16 sB[2][4096];   // [128 cols][32 k]
  __shared__ float wsum[4];

  const int t = threadIdx.x;
  const int w = t >> 6;
  const int lane = t & 63;
  const int rb = blockIdx.x;       // 64 row blocks
  const int cb = blockIdx.y;       // 8 col blocks
  const int row0 = rb * 128;
  const int col0 = cb * 128;
  const int nkb = 4 * (cb + 1);    // triangular: only k-blocks with j <= i_max

  const f32x4 vzero = {0.f, 0.f, 0.f, 0.f};
  f32x4 acc[4][4];
#pragma unroll
  for (int i = 0; i < 4; i++)
#pragma unroll
    for (int j = 0; j < 4; j++) acc[i][j] = vzero;

  // staging: each thread loads 16B; wave w covers 16 rows per call (1 KiB contiguous LDS)
  const int srow = w * 16 + (lane >> 2);
  const int scol = (lane & 3) * 8;
  const int sloff = w * 512 + lane * 8;    // LDS element offset, call 1

  const __hip_bfloat16* gA0 = du + (size_t)(row0 + srow) * 1024 + scol;
  const __hip_bfloat16* gB0 = Mt + (size_t)(col0 + srow) * 1024 + scol;

  auto stage = [&](int buf, int kb) {
    const int kc = kb * 32;
    load_lds16(gA0 + kc,             (void*)&sA[buf][sloff]);
    load_lds16(gA0 + 64 * 1024 + kc, (void*)&sA[buf][2048 + sloff]);
    load_lds16(gB0 + kc,             (void*)&sB[buf][sloff]);
    load_lds16(gB0 + 64 * 1024 + kc, (void*)&sB[buf][2048 + sloff]);
  };

  const int wm = w >> 1, wn = w & 1;
  const int frow = lane & 15;
  const int kch = (lane >> 4) * 8;   // A/B use the SAME k-slot map -> any k-permutation cancels

  auto compute = [&](int buf) {
    bf16x8 aF[4], bF[4];
#pragma unroll
    for (int fm = 0; fm < 4; fm++)
      aF[fm] = *(const bf16x8*)&sA[buf][(wm * 64 + fm * 16 + frow) * 32 + kch];
#pragma unroll
    for (int fn = 0; fn < 4; fn++)
      bF[fn] = *(const bf16x8*)&sB[buf][(wn * 64 + fn * 16 + frow) * 32 + kch];
#pragma unroll
    for (int fm = 0; fm < 4; fm++)
#pragma unroll
      for (int fn = 0; fn < 4; fn++)
        acc[fm][fn] = __builtin_amdgcn_mfma_f32_16x16x32_bf16(aF[fm], bF[fn], acc[fm][fn], 0, 0, 0);
  };

  stage(0, 0);
  for (int kb = 0; kb < nkb; kb++) {
    __syncthreads();                            // tile kb resident (barrier drains vmcnt)
    if (kb + 1 < nkb) stage((kb + 1) & 1, kb + 1);
    compute(kb & 1);
  }

  // fused epilogue: C/D layout col = lane&15, row = (lane>>4)*4 + reg  [HW-verified]
  float psum = 0.f;
  const int rbase = row0 + wm * 64 + (lane >> 4) * 4;
  const int ibase = col0 + wn * 64 + frow;
#pragma unroll
  for (int fm = 0; fm < 4; fm++) {
#pragma unroll
    for (int fn = 0; fn < 4; fn++) {
      const int icol = ibase + fn * 16;        // du index i; output position n = i+1
      if (icol < 1023) {
#pragma unroll
        for (int reg = 0; reg < 4; reg++) {
          const int r = rbase + fm * 16 + reg;
          float frac = COEF * acc[fm][fn][reg];
          float dui = __bfloat162float(du[(size_t)r * 1024 + icol]);
          float ut;
          if (icol == 1022) {
            ut = dui;                           // n = N-1 edge: u_t = du[N-2]
          } else {
            float dui1 = __bfloat162float(du[(size_t)r * 1024 + icol + 1]);
            ut = 0.5f * (dui + dui1);           // central difference
          }
          float res = ut - frac;
          psum += res * res;
        }
      }
    }
  }

#pragma unroll
  for (int off = 32; off > 0; off >>= 1) psum += __shfl_down(psum, off, 64);
  if (lane == 0) wsum[w] = psum;
  __syncthreads();
  if (t == 0) atomicAdd(&accums[1], wsum[0] + wsum[1] + wsum[2] + wsum[3]);
}

__global__ void finalize(const float* __restrict__ accums, float* __restrict__ out) {
  if (threadIdx.x == 0) {
    float data = accums[0] * INV_COUNT;
    float phys = accums[1] * INV_COUNT;
    out[0] = data + 0.1f * phys;
    out[1] = data;
    out[2] = phys;
  }
}

extern "C" void kernel_launch(void* const* d_in, const int* in_sizes, int n_in,
                              void* d_out, int out_size, void* d_ws, size_t ws_size,
                              hipStream_t stream) {
  const float* u_pred = (const float*)d_in[0];
  const float* u_true = (const float*)d_in[1];
  float* out = (float*)d_out;

  char* ws = (char*)d_ws;
  float* accums = (float*)ws;                                   // 2 floats
  __hip_bfloat16* Mt = (__hip_bfloat16*)(ws + 1024);            // 1024*1024*2 = 2 MiB
  __hip_bfloat16* du = (__hip_bfloat16*)(ws + 1024 + 2097152);  // 8192*1024*2 = 16 MiB

  zero_accums<<<1, 64, 0, stream>>>(accums);
  build_mt<<<4096, 256, 0, stream>>>(Mt);
  prep<<<8192, 256, 0, stream>>>(u_pred, u_true, du, accums);
  gemm<<<dim3(64, 8), 256, 0, stream>>>(du, Mt, accums);
  finalize<<<1, 1, 0, stream>>>(accums, out);
}

// Round 2
// 57.610 us; speedup vs baseline: 4.3863x; 4.3863x over previous
//
#include <hip/hip_runtime.h>
#include <hip/hip_bf16.h>

// Problem constants: B=32, T=256, N=1024 -> R = 8192 rows, K = N-1 = 1023 (padded to 1024)
// alpha = 0.5, b[m] = sqrt(m+1)-sqrt(m), coef = sqrt(1023)/Gamma(1.5)
#define COEF 36.090511f
#define INV_COUNT (1.0f / 8388608.0f)   // 1 / (32*256*1024)

typedef __attribute__((ext_vector_type(4))) float f32x4;
typedef __attribute__((ext_vector_type(8))) __bf16 bf16x8;

typedef const __attribute__((address_space(1))) unsigned int* gas_ptr;
typedef __attribute__((address_space(3))) unsigned int* las_ptr;

__device__ __forceinline__ void load_lds16(const void* g, void* l) {
  __builtin_amdgcn_global_load_lds((gas_ptr)g, (las_ptr)l, 16, 0, 0);
}

// Mt[i][j] = b[i-j] for j <= i, else 0.  (transposed Toeplitz so B-tiles are [col][k] row-major)
__global__ void build_mt(__hip_bfloat16* __restrict__ Mt) {
  int idx = blockIdx.x * 256 + threadIdx.x;   // 1024*1024 elements
  int i = idx >> 10;
  int j = idx & 1023;
  int m = i - j;
  float v = (m >= 0) ? (sqrtf((float)(m + 1)) - sqrtf((float)m)) : 0.f;
  Mt[idx] = __float2bfloat16(v);
}

// du (bf16, padded col 1023 = 0); per-block partials instead of atomics
// (8192 same-address atomicAdds serialized at L2 = 213us last round).
__global__ void prep(const float* __restrict__ up, const float* __restrict__ utr,
                     __hip_bfloat16* __restrict__ du,
                     float* __restrict__ dpart, float* __restrict__ ppart) {
  const int r = blockIdx.x;       // 8192 rows
  const int t = threadIdx.x;      // 256 threads
  const int j0 = t * 4;
  const float* rowp = up + (size_t)r * 1024;

  f32x4 a = *(const f32x4*)(rowp + j0);
  float a4 = (t < 255) ? rowp[j0 + 4] : 0.f;
  f32x4 b = *(const f32x4*)(utr + (size_t)r * 1024 + j0);

  float d0 = a[1] - a[0];
  float d1 = a[2] - a[1];
  float d2 = a[3] - a[2];
  float d3 = (t < 255) ? (a4 - a[3]) : 0.f;   // du[1023] = 0 pad

  union { ushort4 u4; __hip_bfloat16 h[4]; } pk;
  pk.h[0] = __float2bfloat16(d0);
  pk.h[1] = __float2bfloat16(d1);
  pk.h[2] = __float2bfloat16(d2);
  pk.h[3] = __float2bfloat16(d3);
  *(ushort4*)(du + (size_t)r * 1024 + j0) = pk.u4;

  float e0 = a[0] - b[0], e1 = a[1] - b[1], e2 = a[2] - b[2], e3 = a[3] - b[3];
  float dsum = e0 * e0 + e1 * e1 + e2 * e2 + e3 * e3;

#pragma unroll
  for (int off = 32; off > 0; off >>= 1) dsum += __shfl_down(dsum, off, 64);
  __shared__ float ws4[4];
  const int lane = t & 63, w = t >> 6;
  if (lane == 0) ws4[w] = dsum;
  __syncthreads();
  if (t == 0) {
    dpart[r] = ws4[0] + ws4[1] + ws4[2] + ws4[3];
    ppart[r] = d0 * d0;   // physics residual at n=0: u_t = du[r,0], frac_lap[0] = 0
  }
}

// Y[r,i] = sum_j du[r,j] * b[i-j]; fused epilogue: resid = u_t - COEF*Y, accumulate resid^2.
// 128x128 tile, BK=32, 4 waves (2x2 of 64x64), double-buffered LDS, triangular K-skip.
__launch_bounds__(256, 2)
__global__ void gemm(const __hip_bfloat16* __restrict__ du,
                     const __hip_bfloat16* __restrict__ Mt,
                     float* __restrict__ gpart) {
  __shared__ __hip_bfloat16 sA[2][4096];   // [128 rows][32 k]
  __shared__ __hip_bfloat16 sB[2][4096];   // [128 cols][32 k]
  __shared__ float wsum[4];

  const int t = threadIdx.x;
  const int w = t >> 6;
  const int lane = t & 63;
  const int rb = blockIdx.x;       // 64 row blocks
  const int cb = blockIdx.y;       // 8 col blocks
  const int row0 = rb * 128;
  const int col0 = cb * 128;
  const int nkb = 4 * (cb + 1);    // triangular: only k-blocks with j <= i_max

  const f32x4 vzero = {0.f, 0.f, 0.f, 0.f};
  f32x4 acc[4][4];
#pragma unroll
  for (int i = 0; i < 4; i++)
#pragma unroll
    for (int j = 0; j < 4; j++) acc[i][j] = vzero;

  const int srow = w * 16 + (lane >> 2);
  const int scol = (lane & 3) * 8;
  const int sloff = w * 512 + lane * 8;

  const __hip_bfloat16* gA0 = du + (size_t)(row0 + srow) * 1024 + scol;
  const __hip_bfloat16* gB0 = Mt + (size_t)(col0 + srow) * 1024 + scol;

  auto stage = [&](int buf, int kb) {
    const int kc = kb * 32;
    load_lds16(gA0 + kc,             (void*)&sA[buf][sloff]);
    load_lds16(gA0 + 64 * 1024 + kc, (void*)&sA[buf][2048 + sloff]);
    load_lds16(gB0 + kc,             (void*)&sB[buf][sloff]);
    load_lds16(gB0 + 64 * 1024 + kc, (void*)&sB[buf][2048 + sloff]);
  };

  const int wm = w >> 1, wn = w & 1;
  const int frow = lane & 15;
  const int kch = (lane >> 4) * 8;   // A/B use the SAME k-slot map -> any k-permutation cancels

  auto compute = [&](int buf) {
    bf16x8 aF[4], bF[4];
#pragma unroll
    for (int fm = 0; fm < 4; fm++)
      aF[fm] = *(const bf16x8*)&sA[buf][(wm * 64 + fm * 16 + frow) * 32 + kch];
#pragma unroll
    for (int fn = 0; fn < 4; fn++)
      bF[fn] = *(const bf16x8*)&sB[buf][(wn * 64 + fn * 16 + frow) * 32 + kch];
#pragma unroll
    for (int fm = 0; fm < 4; fm++)
#pragma unroll
      for (int fn = 0; fn < 4; fn++)
        acc[fm][fn] = __builtin_amdgcn_mfma_f32_16x16x32_bf16(aF[fm], bF[fn], acc[fm][fn], 0, 0, 0);
  };

  stage(0, 0);
  for (int kb = 0; kb < nkb; kb++) {
    __syncthreads();                            // tile kb resident (barrier drains vmcnt)
    if (kb + 1 < nkb) stage((kb + 1) & 1, kb + 1);
    compute(kb & 1);
  }

  // fused epilogue: C/D layout col = lane&15, row = (lane>>4)*4 + reg  [HW-verified]
  float psum = 0.f;
  const int rbase = row0 + wm * 64 + (lane >> 4) * 4;
  const int ibase = col0 + wn * 64 + frow;
#pragma unroll
  for (int fm = 0; fm < 4; fm++) {
#pragma unroll
    for (int fn = 0; fn < 4; fn++) {
      const int icol = ibase + fn * 16;        // du index i; output position n = i+1
      if (icol < 1023) {
#pragma unroll
        for (int reg = 0; reg < 4; reg++) {
          const int r = rbase + fm * 16 + reg;
          float frac = COEF * acc[fm][fn][reg];
          float dui = __bfloat162float(du[(size_t)r * 1024 + icol]);
          float ut;
          if (icol == 1022) {
            ut = dui;                           // n = N-1 edge: u_t = du[N-2]
          } else {
            float dui1 = __bfloat162float(du[(size_t)r * 1024 + icol + 1]);
            ut = 0.5f * (dui + dui1);           // central difference
          }
          float res = ut - frac;
          psum += res * res;
        }
      }
    }
  }

#pragma unroll
  for (int off = 32; off > 0; off >>= 1) psum += __shfl_down(psum, off, 64);
  if (lane == 0) wsum[w] = psum;
  __syncthreads();
  if (t == 0) gpart[cb * 64 + rb] = wsum[0] + wsum[1] + wsum[2] + wsum[3];
}

// Single-block tree reduction of all partials -> 3 outputs. ~17k loads, trivial.
__global__ void finalize(const float* __restrict__ dpart, const float* __restrict__ ppart,
                         const float* __restrict__ gpart, float* __restrict__ out) {
  const int t = threadIdx.x;    // 256 threads
  float ds = 0.f, ps = 0.f;
  for (int i = t; i < 8192; i += 256) { ds += dpart[i]; ps += ppart[i]; }
  for (int i = t; i < 512; i += 256) ps += gpart[i];

#pragma unroll
  for (int off = 32; off > 0; off >>= 1) {
    ds += __shfl_down(ds, off, 64);
    ps += __shfl_down(ps, off, 64);
  }
  __shared__ float sd[4], sp[4];
  const int lane = t & 63, w = t >> 6;
  if (lane == 0) { sd[w] = ds; sp[w] = ps; }
  __syncthreads();
  if (t == 0) {
    float data = (sd[0] + sd[1] + sd[2] + sd[3]) * INV_COUNT;
    float phys = (sp[0] + sp[1] + sp[2] + sp[3]) * INV_COUNT;
    out[0] = data + 0.1f * phys;
    out[1] = data;
    out[2] = phys;
  }
}

extern "C" void kernel_launch(void* const* d_in, const int* in_sizes, int n_in,
                              void* d_out, int out_size, void* d_ws, size_t ws_size,
                              hipStream_t stream) {
  const float* u_pred = (const float*)d_in[0];
  const float* u_true = (const float*)d_in[1];
  float* out = (float*)d_out;

  char* ws = (char*)d_ws;
  float* dpart = (float*)ws;                                    // 8192 floats (32 KiB)
  float* ppart = (float*)(ws + 32768);                          // 8192 floats (32 KiB)
  float* gpart = (float*)(ws + 65536);                          // 512 floats (2 KiB)
  __hip_bfloat16* Mt = (__hip_bfloat16*)(ws + 131072);          // 1024*1024*2 = 2 MiB
  __hip_bfloat16* du = (__hip_bfloat16*)(ws + 131072 + 2097152);// 8192*1024*2 = 16 MiB

  build_mt<<<4096, 256, 0, stream>>>(Mt);
  prep<<<8192, 256, 0, stream>>>(u_pred, u_true, du, dpart, ppart);
  gemm<<<dim3(64, 8), 256, 0, stream>>>(du, Mt, gpart);
  finalize<<<1, 256, 0, stream>>>(dpart, ppart, gpart, out);
}